// Round 11
// baseline (5922.000 us; speedup 1.0000x reference)
//
#include <hip/hip_runtime.h>
#include <hip/hip_bf16.h>
#include <cstdint>
#include <cstddef>

#define B_    32
#define S_    512
#define IN_   256
#define HID_  512
#define NGATE 1024
#define OUT_  256
#define NWGD  16         // worker WGs per direction (each owns 32 r/u/cand cols)

typedef float f32x4 __attribute__((ext_vector_type(4)));
typedef short bf16x8 __attribute__((ext_vector_type(8)));
typedef unsigned long long ull;

__device__ inline unsigned short f2bf(float f) {
  return __builtin_bit_cast(unsigned short, __float2bfloat16(f));
}
__device__ inline float bf2f(unsigned short u) {
  union { float f; unsigned int i; } v; v.i = ((unsigned int)u) << 16; return v.f;
}

// write-through stores: bypass L1/L2 dirty state, land at IF$ (device
// coherent point).  R1/R2/R3/R7/R9-verified.
__device__ inline void store_short_wt(unsigned short* p, unsigned short val) {
  unsigned int v = val;
  asm volatile("global_store_short %0, %1, off sc0 sc1" :: "v"(p), "v"(v) : "memory");
}
__device__ inline void store_dword_wt(unsigned* p, unsigned val) {
  asm volatile("global_store_dword %0, %1, off sc0 sc1" :: "v"(p), "v"(val) : "memory");
}

// ---------------------------------------------------------------- prep ----
__global__ void prep_kernel(const float* __restrict__ x,
                            const float* __restrict__ fcw,
                            unsigned short* __restrict__ Xbf,
                            unsigned short* __restrict__ HFW,
                            unsigned short* __restrict__ HBW,
                            float* __restrict__ pool,
                            unsigned* __restrict__ sync,
                            unsigned short* __restrict__ fcwf)
{
  const int nthreads = gridDim.x * blockDim.x;
  const int gtid = blockIdx.x * blockDim.x + threadIdx.x;

  // x [B,S,IN] -> Xbf [S][B][IN] bf16
  for (int i = gtid; i < S_*B_*IN_; i += nthreads) {
    int c = i & (IN_-1);
    int rem = i >> 8;
    int b = rem & (B_-1);
    int s = rem >> 5;
    Xbf[((size_t)s*B_ + b)*IN_ + c] = f2bf(x[((size_t)b*S_ + s)*IN_ + c]);
  }
  // HFW[0] = 0 (h_{-1}), HBW[S-1] = 0 (hb_S)
  for (int i = gtid; i < B_*HID_; i += nthreads) {
    HFW[i] = 0;
    HBW[(size_t)(S_-1)*B_*HID_ + i] = 0;
  }
  for (int i = gtid; i < B_*HID_; i += nthreads) pool[i] = 0.f;
  for (int i = gtid; i < 4096;    i += nthreads) sync[i] = 0u;
  // fc_w [1280][512] -> fragment order [kc=40][nt=32][lane=64][8]
  for (int i = gtid; i < 40*32*64*8; i += nthreads) {
    int j     = i & 7;
    int lane_ = (i >> 3) & 63;
    int nt    = (i >> 9) & 31;
    int kc    = i >> 14;
    int k = kc*32 + (lane_ >> 4)*8 + j;
    int n = nt*16 + (lane_ & 15);
    fcwf[i] = f2bf(fcw[(size_t)k*HID_ + n]);
  }
}

// ------------------------------------------------------------- pregemm ----
// GX[dir][t*32+b][1024] = x_{t,b} @ Wg[0:256,:] + bg   (bf16)  [R3-verified]
// GC[dir][t*32+b][512]  = x_{t,b} @ Wc[0:256,:] + bc   (bf16)
__global__ __launch_bounds__(256, 1)
void pregemm_kernel(const unsigned short* __restrict__ Xbf,
                    const float* __restrict__ Wg_fw, const float* __restrict__ bg_fw,
                    const float* __restrict__ Wc_fw, const float* __restrict__ bc_fw,
                    const float* __restrict__ Wg_bw, const float* __restrict__ bg_bw,
                    const float* __restrict__ Wc_bw, const float* __restrict__ bc_bw,
                    unsigned short* __restrict__ GX, unsigned short* __restrict__ GC)
{
  __shared__ unsigned short bsm[4*8*64*8];   // 32KB [nt4][kk8][lane][8]
  const int id  = blockIdx.x;                // 0..12287
  const int dir = id >= 6144;
  const int r0  = id - dir*6144;
  const int mtile = r0 / 24;
  const int sec   = r0 % 24;
  const bool isG  = sec < 16;
  const float* W    = dir ? (isG ? Wg_bw : Wc_bw) : (isG ? Wg_fw : Wc_fw);
  const float* bias = dir ? (isG ? bg_bw : bc_bw) : (isG ? bg_fw : bc_fw);
  const int N     = isG ? NGATE : HID_;
  const int nbase = (isG ? sec : sec - 16) * 64;
  unsigned short* out = isG ? (GX + (size_t)dir*16384*NGATE)
                            : (GC + (size_t)dir*16384*HID_);
  const int m0 = mtile * 64;
  const int tid = threadIdx.x, wave = tid >> 6, lane = tid & 63;
  const int quad = lane >> 4, l16 = lane & 15;

  for (int idx = tid; idx < 4*8*64; idx += 256) {
    int lane_ = idx & 63, kk = (idx >> 6) & 7, nt = idx >> 9;
    int n  = nbase + nt*16 + (lane_ & 15);
    int kb = kk*32 + (lane_ >> 4)*8;
    #pragma unroll
    for (int j = 0; j < 8; ++j)
      bsm[((nt*8 + kk)*64 + lane_)*8 + j] = f2bf(W[(size_t)(kb + j)*N + n]);
  }
  __syncthreads();

  f32x4 acc[4];
  #pragma unroll
  for (int nt = 0; nt < 4; ++nt) acc[nt] = (f32x4){0.f,0.f,0.f,0.f};
  #pragma unroll
  for (int kk = 0; kk < 8; ++kk) {
    bf16x8 af = *(const bf16x8*)(Xbf + (size_t)(m0 + wave*16 + l16)*IN_ + quad*8 + kk*32);
    #pragma unroll
    for (int nt = 0; nt < 4; ++nt) {
      bf16x8 bv = *(const bf16x8*)(&bsm[((nt*8 + kk)*64 + lane)*8]);
      acc[nt] = __builtin_amdgcn_mfma_f32_16x16x32_bf16(af, bv, acc[nt], 0, 0, 0);
    }
  }
  #pragma unroll
  for (int nt = 0; nt < 4; ++nt)
    #pragma unroll
    for (int r = 0; r < 4; ++r) {
      int row = m0 + wave*16 + quad*4 + r;
      int col = nbase + nt*16 + l16;
      out[(size_t)row*N + col] = f2bf(acc[nt][r] + bias[col]);
    }
}

// ----------------------------------------------------------- barrier ----
// Wave-autonomous: each producing WAVE drains its own wt-stores (vmcnt(0))
// and posts a sub-flag; consumers poll all 64 sub-flags (16 WG x 4 waves,
// one per lane) with agent-relaxed atomic loads.  No block-sync release.
__device__ inline void wait_flags64(const unsigned* base, unsigned target) {
  const unsigned* p = base + (threadIdx.x & 63)*16;
  for (;;) {
    unsigned v = __hip_atomic_load(p, __ATOMIC_RELAXED, __HIP_MEMORY_SCOPE_AGENT);
    if (!__any((int)(v < target))) break;
    __builtin_amdgcn_s_sleep(1);
  }
}

// --------------------------------------------------------------- gru ----
// 32 WGs x 512 threads: blockIdx>>4 = dir, &15 = column-slice g.
// WG g owns r cols [g*32,+32), u cols [512+g*32,+32), cand cols [g*32,+32).
// Per step: ONE block-sync (u_lds), two flag exchanges.  Producing lanes
// wt-store results directly (scattered shorts); per-wave drain + sub-flag.
__global__ __launch_bounds__(512, 1)
void gru_kernel(const float* __restrict__ Wg_fw, const float* __restrict__ Wc_fw,
                const float* __restrict__ Wg_bw, const float* __restrict__ Wc_bw,
                const unsigned short* __restrict__ GX, const unsigned short* __restrict__ GC,
                unsigned short* __restrict__ HFW, unsigned short* __restrict__ HBW,
                unsigned short* __restrict__ RH, unsigned* __restrict__ sync)
{
  __shared__ __align__(16) unsigned short wg_lds[4][16][512];  // 64KB gate B-frags
  __shared__ __align__(16) unsigned short wc_lds[2][16][512];  // 32KB cand B-frags
  __shared__ float u_lds[32][32];                              // 4KB u gate

  const int dir = blockIdx.x >> 4;
  const int g   = blockIdx.x & 15;
  const int tid = threadIdx.x;
  const int wave = tid >> 6, lane = tid & 63;
  const int quad = lane >> 4, l16 = lane & 15;

  const float* Wg = dir ? Wg_bw : Wg_fw;
  const float* Wc = dir ? Wc_bw : Wc_fw;
  unsigned short* H = dir ? HBW : HFW;                 // [S][B][HID]
  unsigned short* RHd = RH + (size_t)dir*S_*B_*HID_;   // [S][B][HID]
  const unsigned short* GXd = GX + (size_t)dir*16384*NGATE;
  const unsigned short* GCd = GC + (size_t)dir*16384*HID_;
  unsigned* fA = sync + dir*2048;           // 64 sub-flags x 16 dwords
  unsigned* fB = sync + dir*2048 + 1024;

  // ---- stage weight h-rows (256..767) into LDS as B-fragments ----
  for (int idx = tid; idx < 4*16*64; idx += 512) {
    int lane_ = idx & 63, kk = (idx >> 6) & 15, nt = idx >> 10;
    int l16_ = lane_ & 15;
    int n = (nt < 2) ? (g*32 + nt*16 + l16_) : (512 + g*32 + (nt-2)*16 + l16_);
    int kb = IN_ + kk*32 + (lane_ >> 4)*8;
    #pragma unroll
    for (int j = 0; j < 8; ++j)
      wg_lds[nt][kk][lane_*8 + j] = f2bf(Wg[(size_t)(kb + j)*NGATE + n]);
  }
  for (int idx = tid; idx < 2*16*64; idx += 512) {
    int lane_ = idx & 63, kk = (idx >> 6) & 15, nt = idx >> 10;
    int n  = g*32 + nt*16 + (lane_ & 15);
    int kb = IN_ + kk*32 + (lane_ >> 4)*8;
    #pragma unroll
    for (int j = 0; j < 8; ++j)
      wc_lds[nt][kk][lane_*8 + j] = f2bf(Wc[(size_t)(kb + j)*HID_ + n]);
  }
  __syncthreads();

  const int amt = wave >> 2, ant = wave & 3;          // phase A: 2mt x 4nt
  const int b0A = amt*16 + quad*4;
  const int bmt = wave & 1, bnt = (wave >> 1) & 1;    // phase B tiles (waves 0-3)
  const int b0B = bmt*16 + quad*4;
  const int colB = g*32 + bnt*16 + l16;
  // fA sub-flag producers: r-waves {0,1,4,5} -> index 0..3
  const int wiA = (wave & 1) | ((wave >> 2) << 1);
  unsigned* myfA = fA + (g*4 + wiA)*16;
  unsigned* myfB = fB + (g*4 + wave)*16;              // waves 0-3 only

  for (int si = 0; si < S_; ++si) {
    const int t  = dir ? (S_-1-si) : si;
    const int to = dir ? (t-1)     : (t+1);
    const unsigned short* Ht = H + (size_t)t*B_*HID_;

    wait_flags64(fB, (unsigned)si);         // h_prev (H[t]) fully posted

    // ======== phase A: gates = sigmoid(h_prev @ Wg_h + GX[t]) ========
    float gcv[4], hpB[4];                   // phase-B prefetch (waves 0-3)
    {
      const int colg = (ant < 2) ? (g*32 + ant*16 + l16)
                                 : (512 + g*32 + (ant-2)*16 + l16);
      const unsigned short* gx = GXd + (size_t)t*B_*NGATE;
      float gxv[4];
      #pragma unroll
      for (int r = 0; r < 4; ++r) gxv[r] = bf2f(gx[(size_t)(b0A + r)*NGATE + colg]);
      float hpA[4];
      if (ant < 2) {
        #pragma unroll
        for (int r = 0; r < 4; ++r) hpA[r] = bf2f(Ht[(size_t)(b0A + r)*HID_ + colg]);
      }
      if (wave < 4) {
        #pragma unroll
        for (int r = 0; r < 4; ++r) {
          gcv[r] = bf2f(GCd[((size_t)t*B_ + b0B + r)*HID_ + colB]);
          hpB[r] = bf2f(Ht[(size_t)(b0B + r)*HID_ + colB]);
        }
      }
      // direct 16B A-frag loads (fresh-after-flag, R9-verified)
      const unsigned short* arow = Ht + (size_t)(amt*16 + l16)*HID_ + quad*8;
      f32x4 a0 = {0.f,0.f,0.f,0.f}, a1 = {0.f,0.f,0.f,0.f};
      #pragma unroll
      for (int kk = 0; kk < 16; ++kk) {
        bf16x8 af = *(const bf16x8*)(arow + kk*32);
        bf16x8 bv = *(const bf16x8*)(&wg_lds[ant][kk][lane*8]);
        if (kk & 1) a1 = __builtin_amdgcn_mfma_f32_16x16x32_bf16(af, bv, a1, 0, 0, 0);
        else        a0 = __builtin_amdgcn_mfma_f32_16x16x32_bf16(af, bv, a0, 0, 0, 0);
      }
      f32x4 acc = a0 + a1;
      if (ant < 2) {                        // r -> r*h scattered wt-stores
        #pragma unroll
        for (int r = 0; r < 4; ++r) {
          float rv = 1.f / (1.f + __expf(-(acc[r] + gxv[r])));
          store_short_wt(&RHd[(size_t)t*B_*HID_ + (size_t)(b0A + r)*HID_ + colg],
                         f2bf(rv * hpA[r]));
        }
        asm volatile("s_waitcnt vmcnt(0)" ::: "memory");   // per-wave drain
        if (lane == 0) store_dword_wt(myfA, (unsigned)(si + 1));
      } else {                              // u -> LDS (WG-local)
        #pragma unroll
        for (int r = 0; r < 4; ++r)
          u_lds[b0A + r][(ant-2)*16 + l16] = 1.f / (1.f + __expf(-(acc[r] + gxv[r])));
      }
    }
    __syncthreads();                        // u_lds visibility (only block sync)

    // ======== phase B (waves 0-3): c = tanh(rh @ Wc_h + GC); h update ====
    if (wave < 4) {
      wait_flags64(fA, (unsigned)(si + 1));
      const unsigned short* rrow = RHd + (size_t)t*B_*HID_
                                 + (size_t)(bmt*16 + l16)*HID_ + quad*8;
      f32x4 a0 = {0.f,0.f,0.f,0.f}, a1 = {0.f,0.f,0.f,0.f};
      #pragma unroll
      for (int kk = 0; kk < 16; ++kk) {
        bf16x8 af = *(const bf16x8*)(rrow + kk*32);
        bf16x8 bv = *(const bf16x8*)(&wc_lds[bnt][kk][lane*8]);
        if (kk & 1) a1 = __builtin_amdgcn_mfma_f32_16x16x32_bf16(af, bv, a1, 0, 0, 0);
        else        a0 = __builtin_amdgcn_mfma_f32_16x16x32_bf16(af, bv, a0, 0, 0, 0);
      }
      f32x4 acc = a0 + a1;
      if (to >= 0 && to < S_) {
        #pragma unroll
        for (int r = 0; r < 4; ++r) {
          float c  = tanhf(acc[r] + gcv[r]);
          float u  = u_lds[b0B + r][bnt*16 + l16];
          float hn = u * hpB[r] + (1.f - u)*c;
          store_short_wt(&H[((size_t)to*B_ + b0B + r)*HID_ + colB], f2bf(hn));
        }
      }
      asm volatile("s_waitcnt vmcnt(0)" ::: "memory");     // per-wave drain
      if (lane == 0) store_dword_wt(myfB, (unsigned)(si + 1));
    }
    // waves 4-7 skip phase B; they stall at next wait_flags64(fB, si+1)
  }
}

// ---------------------------------------------------------------- fc ----
// last[b][t] = [HFW[t] | Xbf[t] | HBW[t]]; pool = max_t relu(last@fcw+fcb)
__global__ __launch_bounds__(512, 1)
void fc_kernel(const unsigned short* __restrict__ HFW, const unsigned short* __restrict__ HBW,
               const unsigned short* __restrict__ Xbf,
               const unsigned short* __restrict__ fcwf, const float* __restrict__ fcb,
               float* __restrict__ pool)
{
  __shared__ unsigned short bsm[32*512];   // 32KB weight chunk (frag order)
  __shared__ float red[8*512];             // 16KB cross-wave max reduce
  const int wg = blockIdx.x;               // 128 WGs: b = wg/4, t-quarter = wg%4
  const int b  = wg >> 2;
  const int tid = threadIdx.x, wave = tid >> 6, lane = tid & 63;
  const int quad = lane >> 4, l16 = lane & 15;
  const int t = (wg & 3)*128 + wave*16 + l16;  // A-operand row = t

  f32x4 acc[32];
  #pragma unroll
  for (int nt = 0; nt < 32; ++nt) acc[nt] = (f32x4){0.f,0.f,0.f,0.f};

  for (int kc = 0; kc < 40; ++kc) {
    __syncthreads();
    const uint4* src = (const uint4*)(fcwf + (size_t)kc*32*512);
    uint4* dst = (uint4*)bsm;
    #pragma unroll
    for (int r = 0; r < 4; ++r) dst[tid + r*512] = src[tid + r*512];
    __syncthreads();

    const unsigned short* ap;
    if (kc < 16)      ap = HFW + ((size_t)t*B_ + b)*HID_ + kc*32 + quad*8;        // c_left
    else if (kc < 24) ap = Xbf + ((size_t)t*B_ + b)*IN_ + (kc - 16)*32 + quad*8;  // x
    else              ap = HBW + ((size_t)t*B_ + b)*HID_ + (kc - 24)*32 + quad*8; // c_right
    const bf16x8 af = *(const bf16x8*)ap;
    #pragma unroll
    for (int nt = 0; nt < 32; ++nt) {
      bf16x8 bfv = *(const bf16x8*)(&bsm[(nt*64 + lane)*8]);
      acc[nt] = __builtin_amdgcn_mfma_f32_16x16x32_bf16(af, bfv, acc[nt], 0, 0, 0);
    }
  }
  #pragma unroll
  for (int nt = 0; nt < 32; ++nt) {
    float m = fmaxf(fmaxf(acc[nt][0], acc[nt][1]), fmaxf(acc[nt][2], acc[nt][3]));
    m = fmaxf(m, __shfl_xor(m, 16, 64));
    m = fmaxf(m, __shfl_xor(m, 32, 64));
    if (quad == 0) red[wave*512 + nt*16 + l16] = m;
  }
  __syncthreads();
  {
    float m = red[tid];
    #pragma unroll
    for (int w = 1; w < 8; ++w) m = fmaxf(m, red[w*512 + tid]);
    m = fmaxf(m + fcb[tid], 0.f);
    atomicMax((int*)&pool[(size_t)b*HID_ + tid], __float_as_int(m));
  }
}

// --------------------------------------------------------------- mlp ----
__global__ void mlp_kernel(const float* __restrict__ pool, const float* __restrict__ w,
                           const float* __restrict__ bias, float* __restrict__ out)
{
  __shared__ float p[HID_];
  const int b = blockIdx.x, tid = threadIdx.x;  // 256 threads
  p[tid]       = pool[(size_t)b*HID_ + tid];
  p[tid + 256] = pool[(size_t)b*HID_ + 256 + tid];
  __syncthreads();
  float acc = bias[tid];
  for (int k = 0; k < HID_; ++k) acc += p[k] * w[(size_t)k*OUT_ + tid];
  out[(size_t)b*OUT_ + tid] = acc;
}

// ------------------------------------------------------------ launch ----
extern "C" void kernel_launch(void* const* d_in, const int* in_sizes, int n_in,
                              void* d_out, int out_size, void* d_ws, size_t ws_size,
                              hipStream_t stream)
{
  const float* x    = (const float*)d_in[0];
  const float* fwWg = (const float*)d_in[1];
  const float* fwbg = (const float*)d_in[2];
  const float* fwWc = (const float*)d_in[3];
  const float* fwbc = (const float*)d_in[4];
  const float* bwWg = (const float*)d_in[5];
  const float* bwbg = (const float*)d_in[6];
  const float* bwWc = (const float*)d_in[7];
  const float* bwbc = (const float*)d_in[8];
  const float* fcw  = (const float*)d_in[9];
  const float* fcb  = (const float*)d_in[10];
  const float* mlpw = (const float*)d_in[11];
  const float* mlpb = (const float*)d_in[12];
  float* out = (float*)d_out;

  char* p = (char*)d_ws;
  auto take = [&](size_t bytes) { char* r = p; p += (bytes + 255) & ~size_t(255); return r; };
  unsigned short* Xbf  = (unsigned short*)take((size_t)S_*B_*IN_*2);          // 8MB
  unsigned short* HFW  = (unsigned short*)take((size_t)S_*B_*HID_*2);         // 16.8MB
  unsigned short* HBW  = (unsigned short*)take((size_t)S_*B_*HID_*2);         // 16.8MB
  unsigned short* GX   = (unsigned short*)take((size_t)2*S_*B_*NGATE*2);      // 67MB
  unsigned short* GC   = (unsigned short*)take((size_t)2*S_*B_*HID_*2);       // 33.6MB
  unsigned short* RH   = (unsigned short*)take((size_t)2*S_*B_*HID_*2);       // 33.6MB
  unsigned short* fcwf = (unsigned short*)take((size_t)40*32*64*8*2);         // 1.25MB
  float*          pool = (float*)take((size_t)B_*HID_*4);
  unsigned*       sync = (unsigned*)take(16384);  // 4096 dwords of sub-flags

  prep_kernel<<<2048, 256, 0, stream>>>(x, fcw, Xbf, HFW, HBW, pool, sync, fcwf);
  pregemm_kernel<<<12288, 256, 0, stream>>>(Xbf, fwWg, fwbg, fwWc, fwbc,
                                            bwWg, bwbg, bwWc, bwbc, GX, GC);
  gru_kernel<<<2*NWGD, 512, 0, stream>>>(fwWg, fwWc, bwWg, bwWc,
                                         GX, GC, HFW, HBW, RH, sync);
  fc_kernel<<<128, 512, 0, stream>>>(HFW, HBW, Xbf, fcwf, fcb, pool);
  mlp_kernel<<<32, 256, 0, stream>>>(pool, mlpw, mlpb, out);
}

// Round 12
// 4539.775 us; speedup vs baseline: 1.3045x; 1.3045x over previous
//
#include <hip/hip_runtime.h>
#include <hip/hip_bf16.h>
#include <cstdint>
#include <cstddef>

#define B_    32
#define S_    512
#define IN_   256
#define HID_  512
#define NGATE 1024
#define OUT_  256
#define NWGD  16         // worker WGs per direction (each owns 32 r/u/cand cols)

typedef float f32x4 __attribute__((ext_vector_type(4)));
typedef short bf16x8 __attribute__((ext_vector_type(8)));
typedef unsigned long long ull;

__device__ inline unsigned short f2bf(float f) {
  return __builtin_bit_cast(unsigned short, __float2bfloat16(f));
}
__device__ inline float bf2f(unsigned short u) {
  union { float f; unsigned int i; } v; v.i = ((unsigned int)u) << 16; return v.f;
}

// write-through stores: bypass L1/L2 dirty state, land at IF$ (device
// coherent point).  R1/R2/R3/R7/R9/R10-verified.
__device__ inline void store_short_wt(unsigned short* p, unsigned short val) {
  unsigned int v = val;
  asm volatile("global_store_short %0, %1, off sc0 sc1" :: "v"(p), "v"(v) : "memory");
}
__device__ inline void store_dword_wt(unsigned* p, unsigned val) {
  asm volatile("global_store_dword %0, %1, off sc0 sc1" :: "v"(p), "v"(val) : "memory");
}

// ---------------------------------------------------------------- prep ----
__global__ void prep_kernel(const float* __restrict__ x,
                            const float* __restrict__ fcw,
                            unsigned short* __restrict__ Xbf,
                            unsigned short* __restrict__ HFW,
                            unsigned short* __restrict__ HBW,
                            float* __restrict__ pool,
                            unsigned* __restrict__ sync,
                            unsigned short* __restrict__ fcwf)
{
  const int nthreads = gridDim.x * blockDim.x;
  const int gtid = blockIdx.x * blockDim.x + threadIdx.x;

  // x [B,S,IN] -> Xbf [S][B][IN] bf16
  for (int i = gtid; i < S_*B_*IN_; i += nthreads) {
    int c = i & (IN_-1);
    int rem = i >> 8;
    int b = rem & (B_-1);
    int s = rem >> 5;
    Xbf[((size_t)s*B_ + b)*IN_ + c] = f2bf(x[((size_t)b*S_ + s)*IN_ + c]);
  }
  // HFW[0] = 0 (h_{-1}), HBW[S-1] = 0 (hb_S)
  for (int i = gtid; i < B_*HID_; i += nthreads) {
    HFW[i] = 0;
    HBW[(size_t)(S_-1)*B_*HID_ + i] = 0;
  }
  for (int i = gtid; i < B_*HID_; i += nthreads) pool[i] = 0.f;
  for (int i = gtid; i < 4096;    i += nthreads) sync[i] = 0u;
  // fc_w [1280][512] -> fragment order [kc=40][nt=32][lane=64][8]
  for (int i = gtid; i < 40*32*64*8; i += nthreads) {
    int j     = i & 7;
    int lane_ = (i >> 3) & 63;
    int nt    = (i >> 9) & 31;
    int kc    = i >> 14;
    int k = kc*32 + (lane_ >> 4)*8 + j;
    int n = nt*16 + (lane_ & 15);
    fcwf[i] = f2bf(fcw[(size_t)k*HID_ + n]);
  }
}

// ------------------------------------------------------------- pregemm ----
// GX[dir][t*32+b][1024] = x_{t,b} @ Wg[0:256,:] + bg   (bf16)  [R3-verified]
// GC[dir][t*32+b][512]  = x_{t,b} @ Wc[0:256,:] + bc   (bf16)
__global__ __launch_bounds__(256, 1)
void pregemm_kernel(const unsigned short* __restrict__ Xbf,
                    const float* __restrict__ Wg_fw, const float* __restrict__ bg_fw,
                    const float* __restrict__ Wc_fw, const float* __restrict__ bc_fw,
                    const float* __restrict__ Wg_bw, const float* __restrict__ bg_bw,
                    const float* __restrict__ Wc_bw, const float* __restrict__ bc_bw,
                    unsigned short* __restrict__ GX, unsigned short* __restrict__ GC)
{
  __shared__ unsigned short bsm[4*8*64*8];   // 32KB [nt4][kk8][lane][8]
  const int id  = blockIdx.x;                // 0..12287
  const int dir = id >= 6144;
  const int r0  = id - dir*6144;
  const int mtile = r0 / 24;
  const int sec   = r0 % 24;
  const bool isG  = sec < 16;
  const float* W    = dir ? (isG ? Wg_bw : Wc_bw) : (isG ? Wg_fw : Wc_fw);
  const float* bias = dir ? (isG ? bg_bw : bc_bw) : (isG ? bg_fw : bc_fw);
  const int N     = isG ? NGATE : HID_;
  const int nbase = (isG ? sec : sec - 16) * 64;
  unsigned short* out = isG ? (GX + (size_t)dir*16384*NGATE)
                            : (GC + (size_t)dir*16384*HID_);
  const int m0 = mtile * 64;
  const int tid = threadIdx.x, wave = tid >> 6, lane = tid & 63;
  const int quad = lane >> 4, l16 = lane & 15;

  for (int idx = tid; idx < 4*8*64; idx += 256) {
    int lane_ = idx & 63, kk = (idx >> 6) & 7, nt = idx >> 9;
    int n  = nbase + nt*16 + (lane_ & 15);
    int kb = kk*32 + (lane_ >> 4)*8;
    #pragma unroll
    for (int j = 0; j < 8; ++j)
      bsm[((nt*8 + kk)*64 + lane_)*8 + j] = f2bf(W[(size_t)(kb + j)*N + n]);
  }
  __syncthreads();

  f32x4 acc[4];
  #pragma unroll
  for (int nt = 0; nt < 4; ++nt) acc[nt] = (f32x4){0.f,0.f,0.f,0.f};
  #pragma unroll
  for (int kk = 0; kk < 8; ++kk) {
    bf16x8 af = *(const bf16x8*)(Xbf + (size_t)(m0 + wave*16 + l16)*IN_ + quad*8 + kk*32);
    #pragma unroll
    for (int nt = 0; nt < 4; ++nt) {
      bf16x8 bv = *(const bf16x8*)(&bsm[((nt*8 + kk)*64 + lane)*8]);
      acc[nt] = __builtin_amdgcn_mfma_f32_16x16x32_bf16(af, bv, acc[nt], 0, 0, 0);
    }
  }
  #pragma unroll
  for (int nt = 0; nt < 4; ++nt)
    #pragma unroll
    for (int r = 0; r < 4; ++r) {
      int row = m0 + wave*16 + quad*4 + r;
      int col = nbase + nt*16 + l16;
      out[(size_t)row*N + col] = f2bf(acc[nt][r] + bias[col]);
    }
}

// ----------------------------------------------------------- barrier ----
// 16 per-WG flags, each on its own 64B line.  ALL waves poll independently
// (lane&15 -> flag, 4 lanes per flag) with agent-relaxed atomic loads; no
// block-sync release.  Producer side: one __syncthreads drains every wave's
// wt data stores (vmcnt(0) before s_barrier), then tid0 posts the flag —
// flag-visible implies data-visible (R1-verified ordering).
__device__ inline void wait_flags_aw(const unsigned* base, unsigned target) {
  const unsigned* p = base + (threadIdx.x & (NWGD-1))*16;
  for (;;) {
    unsigned v = __hip_atomic_load(p, __ATOMIC_RELAXED, __HIP_MEMORY_SCOPE_AGENT);
    if (!__any((int)(v < target))) break;
    __builtin_amdgcn_s_sleep(1);
  }
}

// --------------------------------------------------------------- gru ----
// 32 WGs x 512 threads: blockIdx>>4 = dir, &15 = column-slice g.
// WG g owns r cols [g*32,+32), u cols [512+g*32,+32), cand cols [g*32,+32).
// Per step: TWO block-syncs (one per phase, store-drain + u_lds publish),
// direct scattered wt-stores, all-wave flag polling, waves 4-7 skip phase B.
__global__ __launch_bounds__(512, 1)
void gru_kernel(const float* __restrict__ Wg_fw, const float* __restrict__ Wc_fw,
                const float* __restrict__ Wg_bw, const float* __restrict__ Wc_bw,
                const unsigned short* __restrict__ GX, const unsigned short* __restrict__ GC,
                unsigned short* __restrict__ HFW, unsigned short* __restrict__ HBW,
                unsigned short* __restrict__ RH, unsigned* __restrict__ sync)
{
  __shared__ __align__(16) unsigned short wg_lds[4][16][512];  // 64KB gate B-frags
  __shared__ __align__(16) unsigned short wc_lds[2][16][512];  // 32KB cand B-frags
  __shared__ float u_lds[32][32];                              // 4KB u gate

  const int dir = blockIdx.x >> 4;
  const int g   = blockIdx.x & 15;
  const int tid = threadIdx.x;
  const int wave = tid >> 6, lane = tid & 63;
  const int quad = lane >> 4, l16 = lane & 15;

  const float* Wg = dir ? Wg_bw : Wg_fw;
  const float* Wc = dir ? Wc_bw : Wc_fw;
  unsigned short* H = dir ? HBW : HFW;                 // [S][B][HID]
  unsigned short* RHd = RH + (size_t)dir*S_*B_*HID_;   // [S][B][HID]
  const unsigned short* GXd = GX + (size_t)dir*16384*NGATE;
  const unsigned short* GCd = GC + (size_t)dir*16384*HID_;
  unsigned* fA = sync + dir*1024;          // 16 flags x 16-dword spacing
  unsigned* fB = sync + dir*1024 + 512;

  // ---- stage weight h-rows (256..767) into LDS as B-fragments ----
  for (int idx = tid; idx < 4*16*64; idx += 512) {
    int lane_ = idx & 63, kk = (idx >> 6) & 15, nt = idx >> 10;
    int l16_ = lane_ & 15;
    int n = (nt < 2) ? (g*32 + nt*16 + l16_) : (512 + g*32 + (nt-2)*16 + l16_);
    int kb = IN_ + kk*32 + (lane_ >> 4)*8;
    #pragma unroll
    for (int j = 0; j < 8; ++j)
      wg_lds[nt][kk][lane_*8 + j] = f2bf(Wg[(size_t)(kb + j)*NGATE + n]);
  }
  for (int idx = tid; idx < 2*16*64; idx += 512) {
    int lane_ = idx & 63, kk = (idx >> 6) & 15, nt = idx >> 10;
    int n  = g*32 + nt*16 + (lane_ & 15);
    int kb = IN_ + kk*32 + (lane_ >> 4)*8;
    #pragma unroll
    for (int j = 0; j < 8; ++j)
      wc_lds[nt][kk][lane_*8 + j] = f2bf(Wc[(size_t)(kb + j)*HID_ + n]);
  }
  __syncthreads();

  const int amt = wave >> 2, ant = wave & 3;          // phase A: 2mt x 4nt
  const int b0A = amt*16 + quad*4;
  const int bmt = wave & 1, bnt = (wave >> 1) & 1;    // phase B tiles (waves 0-3)
  const int b0B = bmt*16 + quad*4;
  const int colB = g*32 + bnt*16 + l16;

  for (int si = 0; si < S_; ++si) {
    const int t  = dir ? (S_-1-si) : si;
    const int to = dir ? (t-1)     : (t+1);
    const unsigned short* Ht = H + (size_t)t*B_*HID_;

    wait_flags_aw(fB, (unsigned)si);        // h_prev (H[t]) fully posted

    // ======== phase A: gates = sigmoid(h_prev @ Wg_h + GX[t]) ========
    float gcv[4], hpB[4];                   // phase-B prefetch (waves 0-3)
    {
      const int colg = (ant < 2) ? (g*32 + ant*16 + l16)
                                 : (512 + g*32 + (ant-2)*16 + l16);
      const unsigned short* gx = GXd + (size_t)t*B_*NGATE;
      float gxv[4];
      #pragma unroll
      for (int r = 0; r < 4; ++r) gxv[r] = bf2f(gx[(size_t)(b0A + r)*NGATE + colg]);
      float hpA[4];
      if (ant < 2) {
        #pragma unroll
        for (int r = 0; r < 4; ++r) hpA[r] = bf2f(Ht[(size_t)(b0A + r)*HID_ + colg]);
      }
      if (wave < 4) {
        #pragma unroll
        for (int r = 0; r < 4; ++r) {
          gcv[r] = bf2f(GCd[((size_t)t*B_ + b0B + r)*HID_ + colB]);
          hpB[r] = bf2f(Ht[(size_t)(b0B + r)*HID_ + colB]);
        }
      }
      // direct 16B A-frag loads (fresh-after-flag, R9-verified)
      const unsigned short* arow = Ht + (size_t)(amt*16 + l16)*HID_ + quad*8;
      f32x4 a0 = {0.f,0.f,0.f,0.f}, a1 = {0.f,0.f,0.f,0.f};
      #pragma unroll
      for (int kk = 0; kk < 16; ++kk) {
        bf16x8 af = *(const bf16x8*)(arow + kk*32);
        bf16x8 bv = *(const bf16x8*)(&wg_lds[ant][kk][lane*8]);
        if (kk & 1) a1 = __builtin_amdgcn_mfma_f32_16x16x32_bf16(af, bv, a1, 0, 0, 0);
        else        a0 = __builtin_amdgcn_mfma_f32_16x16x32_bf16(af, bv, a0, 0, 0, 0);
      }
      f32x4 acc = a0 + a1;
      if (ant < 2) {                        // r -> r*h direct wt-stores
        #pragma unroll
        for (int r = 0; r < 4; ++r) {
          float rv = 1.f / (1.f + __expf(-(acc[r] + gxv[r])));
          store_short_wt(&RHd[(size_t)t*B_*HID_ + (size_t)(b0A + r)*HID_ + colg],
                         f2bf(rv * hpA[r]));
        }
      } else {                              // u -> LDS (WG-local)
        #pragma unroll
        for (int r = 0; r < 4; ++r)
          u_lds[b0A + r][(ant-2)*16 + l16] = 1.f / (1.f + __expf(-(acc[r] + gxv[r])));
      }
    }
    __syncthreads();                        // drain rh stores + publish u_lds
    if (tid == 0) store_dword_wt(fA + g*16, (unsigned)(si + 1));

    // ======== phase B (waves 0-3): c = tanh(rh @ Wc_h + GC); h update ====
    if (wave < 4) {
      wait_flags_aw(fA, (unsigned)(si + 1));
      const unsigned short* rrow = RHd + (size_t)t*B_*HID_
                                 + (size_t)(bmt*16 + l16)*HID_ + quad*8;
      f32x4 a0 = {0.f,0.f,0.f,0.f}, a1 = {0.f,0.f,0.f,0.f};
      #pragma unroll
      for (int kk = 0; kk < 16; ++kk) {
        bf16x8 af = *(const bf16x8*)(rrow + kk*32);
        bf16x8 bv = *(const bf16x8*)(&wc_lds[bnt][kk][lane*8]);
        if (kk & 1) a1 = __builtin_amdgcn_mfma_f32_16x16x32_bf16(af, bv, a1, 0, 0, 0);
        else        a0 = __builtin_amdgcn_mfma_f32_16x16x32_bf16(af, bv, a0, 0, 0, 0);
      }
      f32x4 acc = a0 + a1;
      if (to >= 0 && to < S_) {
        #pragma unroll
        for (int r = 0; r < 4; ++r) {
          float c  = tanhf(acc[r] + gcv[r]);
          float u  = u_lds[b0B + r][bnt*16 + l16];
          float hn = u * hpB[r] + (1.f - u)*c;
          store_short_wt(&H[((size_t)to*B_ + b0B + r)*HID_ + colB], f2bf(hn));
        }
      }
    }
    __syncthreads();                        // drain h stores (all 8 waves)
    if (tid == 0) store_dword_wt(fB + g*16, (unsigned)(si + 1));
  }
}

// ---------------------------------------------------------------- fc ----
// last[b][t] = [HFW[t] | Xbf[t] | HBW[t]]; pool = max_t relu(last@fcw+fcb)
__global__ __launch_bounds__(512, 1)
void fc_kernel(const unsigned short* __restrict__ HFW, const unsigned short* __restrict__ HBW,
               const unsigned short* __restrict__ Xbf,
               const unsigned short* __restrict__ fcwf, const float* __restrict__ fcb,
               float* __restrict__ pool)
{
  __shared__ unsigned short bsm[32*512];   // 32KB weight chunk (frag order)
  __shared__ float red[8*512];             // 16KB cross-wave max reduce
  const int wg = blockIdx.x;               // 128 WGs: b = wg/4, t-quarter = wg%4
  const int b  = wg >> 2;
  const int tid = threadIdx.x, wave = tid >> 6, lane = tid & 63;
  const int quad = lane >> 4, l16 = lane & 15;
  const int t = (wg & 3)*128 + wave*16 + l16;  // A-operand row = t

  f32x4 acc[32];
  #pragma unroll
  for (int nt = 0; nt < 32; ++nt) acc[nt] = (f32x4){0.f,0.f,0.f,0.f};

  for (int kc = 0; kc < 40; ++kc) {
    __syncthreads();
    const uint4* src = (const uint4*)(fcwf + (size_t)kc*32*512);
    uint4* dst = (uint4*)bsm;
    #pragma unroll
    for (int r = 0; r < 4; ++r) dst[tid + r*512] = src[tid + r*512];
    __syncthreads();

    const unsigned short* ap;
    if (kc < 16)      ap = HFW + ((size_t)t*B_ + b)*HID_ + kc*32 + quad*8;        // c_left
    else if (kc < 24) ap = Xbf + ((size_t)t*B_ + b)*IN_ + (kc - 16)*32 + quad*8;  // x
    else              ap = HBW + ((size_t)t*B_ + b)*HID_ + (kc - 24)*32 + quad*8; // c_right
    const bf16x8 af = *(const bf16x8*)ap;
    #pragma unroll
    for (int nt = 0; nt < 32; ++nt) {
      bf16x8 bfv = *(const bf16x8*)(&bsm[(nt*64 + lane)*8]);
      acc[nt] = __builtin_amdgcn_mfma_f32_16x16x32_bf16(af, bfv, acc[nt], 0, 0, 0);
    }
  }
  #pragma unroll
  for (int nt = 0; nt < 32; ++nt) {
    float m = fmaxf(fmaxf(acc[nt][0], acc[nt][1]), fmaxf(acc[nt][2], acc[nt][3]));
    m = fmaxf(m, __shfl_xor(m, 16, 64));
    m = fmaxf(m, __shfl_xor(m, 32, 64));
    if (quad == 0) red[wave*512 + nt*16 + l16] = m;
  }
  __syncthreads();
  {
    float m = red[tid];
    #pragma unroll
    for (int w = 1; w < 8; ++w) m = fmaxf(m, red[w*512 + tid]);
    m = fmaxf(m + fcb[tid], 0.f);
    atomicMax((int*)&pool[(size_t)b*HID_ + tid], __float_as_int(m));
  }
}

// --------------------------------------------------------------- mlp ----
__global__ void mlp_kernel(const float* __restrict__ pool, const float* __restrict__ w,
                           const float* __restrict__ bias, float* __restrict__ out)
{
  __shared__ float p[HID_];
  const int b = blockIdx.x, tid = threadIdx.x;  // 256 threads
  p[tid]       = pool[(size_t)b*HID_ + tid];
  p[tid + 256] = pool[(size_t)b*HID_ + 256 + tid];
  __syncthreads();
  float acc = bias[tid];
  for (int k = 0; k < HID_; ++k) acc += p[k] * w[(size_t)k*OUT_ + tid];
  out[(size_t)b*OUT_ + tid] = acc;
}

// ------------------------------------------------------------ launch ----
extern "C" void kernel_launch(void* const* d_in, const int* in_sizes, int n_in,
                              void* d_out, int out_size, void* d_ws, size_t ws_size,
                              hipStream_t stream)
{
  const float* x    = (const float*)d_in[0];
  const float* fwWg = (const float*)d_in[1];
  const float* fwbg = (const float*)d_in[2];
  const float* fwWc = (const float*)d_in[3];
  const float* fwbc = (const float*)d_in[4];
  const float* bwWg = (const float*)d_in[5];
  const float* bwbg = (const float*)d_in[6];
  const float* bwWc = (const float*)d_in[7];
  const float* bwbc = (const float*)d_in[8];
  const float* fcw  = (const float*)d_in[9];
  const float* fcb  = (const float*)d_in[10];
  const float* mlpw = (const float*)d_in[11];
  const float* mlpb = (const float*)d_in[12];
  float* out = (float*)d_out;

  char* p = (char*)d_ws;
  auto take = [&](size_t bytes) { char* r = p; p += (bytes + 255) & ~size_t(255); return r; };
  unsigned short* Xbf  = (unsigned short*)take((size_t)S_*B_*IN_*2);          // 8MB
  unsigned short* HFW  = (unsigned short*)take((size_t)S_*B_*HID_*2);         // 16.8MB
  unsigned short* HBW  = (unsigned short*)take((size_t)S_*B_*HID_*2);         // 16.8MB
  unsigned short* GX   = (unsigned short*)take((size_t)2*S_*B_*NGATE*2);      // 67MB
  unsigned short* GC   = (unsigned short*)take((size_t)2*S_*B_*HID_*2);       // 33.6MB
  unsigned short* RH   = (unsigned short*)take((size_t)2*S_*B_*HID_*2);       // 33.6MB
  unsigned short* fcwf = (unsigned short*)take((size_t)40*32*64*8*2);         // 1.25MB
  float*          pool = (float*)take((size_t)B_*HID_*4);
  unsigned*       sync = (unsigned*)take(16384);

  prep_kernel<<<2048, 256, 0, stream>>>(x, fcw, Xbf, HFW, HBW, pool, sync, fcwf);
  pregemm_kernel<<<12288, 256, 0, stream>>>(Xbf, fwWg, fwbg, fwWc, fwbc,
                                            bwWg, bwbg, bwWc, bwbc, GX, GC);
  gru_kernel<<<2*NWGD, 512, 0, stream>>>(fwWg, fwWc, bwWg, bwWc,
                                         GX, GC, HFW, HBW, RH, sync);
  fc_kernel<<<128, 512, 0, stream>>>(HFW, HBW, Xbf, fcwf, fcb, pool);
  mlp_kernel<<<32, 256, 0, stream>>>(pool, mlpw, mlpb, out);
}